// Round 2
// baseline (46.864 us; speedup 1.0000x reference)
//
#include <hip/hip_runtime.h>

// FSRS3 scan: inputs (SEQ, BATCH, 2) f32, w (13) f32.
// out = [outputs (SEQ, BATCH, 2) ; final_state (BATCH, 2)] flat f32.
// Each batch column is an independent 64-step recurrence -> 1 thread per
// 2 columns, float4 streaming loads/stores, prefetch-by-1 on the seq axis.
// Transcendentals via raw gfx builtins (v_exp_f32 / v_log_f32 / v_rcp_f32)
// to avoid the glibc __exp2f host-declaration collision.

constexpr int SEQ   = 64;
constexpr int BATCH = 262144;

__device__ __forceinline__ float fexp2(float x) { return __builtin_amdgcn_exp2f(x); }
__device__ __forceinline__ float flog2(float x) { return __builtin_amdgcn_logf(x); }
__device__ __forceinline__ float frcp(float x)  { return __builtin_amdgcn_rcpf(x); }

__global__ __launch_bounds__(256)
void fsrs3_kernel(const float* __restrict__ in,
                  const float* __restrict__ w_,
                  float* __restrict__ out) {
    const int tid = blockIdx.x * blockDim.x + threadIdx.x;   // 0 .. BATCH/2-1

    // Weights (broadcast loads, L1/L2-cached).
    const float w0 = w_[0],  w1 = w_[1],  w2 = w_[2],  w3 = w_[3];
    const float w4 = w_[4],  w5 = w_[5],  w6 = w_[6],  w7 = w_[7];
    const float w8 = w_[8],  w9 = w_[9],  w10 = w_[10], w11 = w_[11];
    const float w12 = w_[12];

    constexpr float L2E      = 1.44269504088896340736f;   // log2(e)
    constexpr float LOG2_09  = -0.15200309344504997f;     // log2(0.9)
    const float ew6  = fexp2(w6 * L2E);                   // exp(w6)
    const float w8l  = w8  * L2E;
    const float w12l = w12 * L2E;
    const float omw5 = 1.0f - w5;
    const float w52  = w5 * w2;

    const float4* __restrict__ inp  = (const float4*)in;
    float4*       __restrict__ outp = (float4*)out;
    constexpr int RS = BATCH / 2;   // float4 per seq row

    // ---- first step (seq 0): state from rating only ----
    float4 x = inp[tid];
    float s0, d0, s1, d1;
    {
        const float r0 = x.y, r1 = x.w;
        s0 = fminf(fmaxf(w0 + w1 * (r0 - 1.0f), 0.1f), 36500.0f);
        d0 = fminf(fmaxf(w2 + w3 * (r0 - 3.0f), 1.0f), 10.0f);
        s1 = fminf(fmaxf(w0 + w1 * (r1 - 1.0f), 0.1f), 36500.0f);
        d1 = fminf(fmaxf(w2 + w3 * (r1 - 3.0f), 1.0f), 10.0f);
    }
    outp[tid] = make_float4(s0, d0, s1, d1);

    // ---- recurrence, seq 1..63, prefetch next row by one iteration ----
    x = inp[RS + tid];

    auto step = [&](float t, float rating, float& s, float& d) {
        const float r   = fexp2(LOG2_09 * t * frcp(s));   // 0.9^(t/s)
        const float nd  = fminf(fmaxf(w52 + omw5 * (d + w4 * (rating - 3.0f)),
                                      1.0f), 10.0f);
        const float omr = 1.0f - r;
        const float ls  = flog2(s);
        const float e8  = fexp2(omr * w8l);           // exp((1-r)*w8)
        const float e12 = fexp2(omr * w12l);          // exp((1-r)*w12)
        const float p7  = fexp2(w7  * ls);            // s^w7
        const float p11 = fexp2(w11 * ls);            // s^w11
        const float pnd = fexp2(w10 * flog2(nd));     // nd^w10
        const float succ = s * (1.0f + ew6 * (11.0f - nd) * p7 * (e8 - 1.0f));
        const float fail = w9 * pnd * p11 * e12;
        const float ns   = (rating > 1.0f) ? succ : fail;
        s = fminf(fmaxf(ns, 0.1f), 36500.0f);
        d = nd;
    };

    for (int seq = 1; seq < SEQ; ++seq) {
        const int pn = (seq + 1 < SEQ) ? (seq + 1) : (SEQ - 1);
        float4 xn = inp[(long long)pn * RS + tid];     // prefetch next row

        step(x.x, x.y, s0, d0);
        step(x.z, x.w, s1, d1);

        outp[(long long)seq * RS + tid] = make_float4(s0, d0, s1, d1);
        x = xn;
    }

    // ---- final_state duplicate at the tail ----
    outp[(long long)SEQ * RS + tid] = make_float4(s0, d0, s1, d1);
}

extern "C" void kernel_launch(void* const* d_in, const int* in_sizes, int n_in,
                              void* d_out, int out_size, void* d_ws, size_t ws_size,
                              hipStream_t stream) {
    const float* in = (const float*)d_in[0];
    const float* w  = (const float*)d_in[1];
    float* out      = (float*)d_out;

    dim3 block(256);
    dim3 grid((BATCH / 2) / 256);   // 512 blocks
    hipLaunchKernelGGL(fsrs3_kernel, grid, block, 0, stream, in, w, out);
}